// Round 1
// baseline (487.133 us; speedup 1.0000x reference)
//
#include <hip/hip_runtime.h>
#include <hip/hip_bf16.h>
#include <math.h>

// Problem constants (fixed by the reference)
#define N_TOK 4096
#define DIM   1024
#define NEXP  16
#define HID   1536
#define TOPK2 2
#define NASSIGN (N_TOK * TOPK2)   // 8192

#define MAX_ITEMS 80   // worst-case sum_e ceil(ne/128) = 79

typedef __attribute__((ext_vector_type(8))) short short8;   // bf16x8 MFMA A/B frag
typedef __attribute__((ext_vector_type(4))) float floatx4;  // fp32x4 MFMA C/D frag
typedef unsigned short u16;

// async global->LDS, 16B per lane; LDS dest = wave-uniform base + lane*16
#define GLOAD_LDS16(gp, lp)                                                     \
    __builtin_amdgcn_global_load_lds(                                           \
        (const __attribute__((address_space(1))) unsigned int*)(gp),            \
        (__attribute__((address_space(3))) unsigned int*)(lp), 16, 0, 0)

// ---------------- fp32 -> bf16 conversion (vectorized) ----------------
__global__ void cvt_kernel(const float* __restrict__ src, u16* __restrict__ dst, int n4) {
    int i = blockIdx.x * 256 + threadIdx.x;
    if (i >= n4) return;
    float4 v = ((const float4*)src)[i];
    __hip_bfloat16 a = __float2bfloat16(v.x), b = __float2bfloat16(v.y);
    __hip_bfloat16 c = __float2bfloat16(v.z), d = __float2bfloat16(v.w);
    ushort4 o;
    o.x = *(u16*)&a; o.y = *(u16*)&b; o.z = *(u16*)&c; o.w = *(u16*)&d;
    ((ushort4*)dst)[i] = o;
}

// ---------- Router logits + top-2 + gates; also emits x in bf16 ----------
// 256 blocks x 16 tokens. Thread (t,e) = (tid>>4, tid&15) accumulates one logit.
// LDS rows stride 68 floats: float4-store aligned, 2-way bank conflicts max (free).
__global__ __launch_bounds__(256)
void logits_topk_kernel(const float* __restrict__ x, const float* __restrict__ rw,
                        int* __restrict__ idx, float* __restrict__ gate,
                        u16* __restrict__ x_bf) {
    int tb = blockIdx.x * 16;
    __shared__ float xs[16][68];
    __shared__ float rs[16][68];
    __shared__ float lg[16][17];

    int tid = threadIdx.x;
    int t = tid >> 4, e = tid & 15;
    int srow = tid >> 4, scol = (tid & 15) * 4;   // staging: one float4/thread

    float acc = 0.f;
    for (int k0 = 0; k0 < DIM; k0 += 64) {
        float4 xv = *(const float4*)&x[(size_t)(tb + srow) * DIM + k0 + scol];
        *(float4*)&xs[srow][scol] = xv;
        *(float4*)&rs[srow][scol] = *(const float4*)&rw[(size_t)srow * DIM + k0 + scol];
        // fused x -> bf16 (saves a separate conversion pass over 16.8 MB)
        {
            __hip_bfloat16 a = __float2bfloat16(xv.x), b = __float2bfloat16(xv.y);
            __hip_bfloat16 c = __float2bfloat16(xv.z), d = __float2bfloat16(xv.w);
            ushort4 o;
            o.x = *(u16*)&a; o.y = *(u16*)&b; o.z = *(u16*)&c; o.w = *(u16*)&d;
            *(ushort4*)&x_bf[(size_t)(tb + srow) * DIM + k0 + scol] = o;
        }
        __syncthreads();
        const float2* xp = (const float2*)xs[t];
        const float2* rp = (const float2*)rs[e];
        #pragma unroll
        for (int k = 0; k < 32; k++) {
            float2 a = xp[k], b = rp[k];
            acc = fmaf(a.x, b.x, acc);
            acc = fmaf(a.y, b.y, acc);
        }
        __syncthreads();
    }
    lg[t][e] = acc;
    __syncthreads();

    if (tid < 16) {
        int n = tb + tid;
        float v0 = -3.402823466e+38f, v1 = -3.402823466e+38f;
        int i0 = 0, i1 = 0;
        #pragma unroll
        for (int ee = 0; ee < NEXP; ee++) {
            float v = lg[tid][ee];
            if (v > v0) { v1 = v0; i1 = i0; v0 = v; i0 = ee; }
            else if (v > v1) { v1 = v; i1 = ee; }
        }
        float e1 = expf(v1 - v0);
        float inv = 1.f / (1.f + e1);
        idx[2 * n] = i0; idx[2 * n + 1] = i1;
        gate[2 * n] = inv; gate[2 * n + 1] = e1 * inv;
    }
}

// ---- Plan: counts/gsum -> offsets + aux + worklist + scatter (one block) ----
__global__ __launch_bounds__(256)
void plan_kernel(const int* __restrict__ idx, const float* __restrict__ gate,
                 int* __restrict__ offsets, int* __restrict__ tlist,
                 int* __restrict__ wl, int* __restrict__ wcount,
                 float* __restrict__ aux_out) {
    __shared__ int cnt_s[16];
    __shared__ float gs_s[16];
    __shared__ int pos_s[16];
    __shared__ int offs_s[17];
    int tid = threadIdx.x;
    if (tid < 16) { cnt_s[tid] = 0; gs_s[tid] = 0.f; pos_s[tid] = 0; }
    __syncthreads();
    for (int i = tid; i < NASSIGN; i += 256) {
        int e = idx[i];
        atomicAdd(&cnt_s[e], 1);
        atomicAdd(&gs_s[e], gate[i]);
    }
    __syncthreads();
    if (tid == 0) {
        int acc = 0;
        for (int e = 0; e < NEXP; e++) { offs_s[e] = acc; acc += cnt_s[e]; }
        offs_s[NEXP] = acc;
        float tot = (float)acc;
        float s = 0.f;
        for (int e = 0; e < NEXP; e++) {
            float c = (float)cnt_s[e];
            s += (c / tot) * (gs_s[e] / fmaxf(c, 1.f));
        }
        *aux_out = 0.02f * (s / (float)NEXP);
        int m = 0;
        for (int e = 0; e < NEXP; e++) {
            int nt = (cnt_s[e] + 127) >> 7;
            for (int rt = 0; rt < nt; rt++) wl[m++] = (e << 8) | rt;
        }
        *wcount = m;
    }
    __syncthreads();
    if (tid < 17) offsets[tid] = offs_s[tid];
    for (int i = tid; i < NASSIGN; i += 256) {
        int e = idx[i];
        int p = atomicAdd(&pos_s[e], 1);
        tlist[offs_s[e] + p] = i;
    }
}

__device__ __forceinline__ float gelu_tanh(float v) {
    float v3 = v * v * v;
    float t = tanhf(0.7978845608028654f * (v + 0.044715f * v3));
    return 0.5f * v * (1.f + t);
}

// =====================================================================
// MFMA grouped GEMM, 128x128 tile, BK=32 bf16, 4 waves (each 64x64).
// Double-buffered LDS (T3-min): stage next K-tile BEFORE compute of the
// current one, single __syncthreads per step (its vmcnt(0) drain is now
// covered by a full ds_read+MFMA phase instead of being fully exposed).
// =====================================================================

// GEMM1: h[a, :] = gelu(x[tok(a)] @ w1[e]^T + b1[e]),  K=DIM=1024, N=HID=1536
__global__ __launch_bounds__(256)
void gemm1_kernel(const u16* __restrict__ xb, const u16* __restrict__ w1b,
                  const float* __restrict__ b1,
                  const int* __restrict__ offsets, const int* __restrict__ tlist,
                  const int* __restrict__ wl, const int* __restrict__ wcount,
                  u16* __restrict__ h_bf) {
    int bid = blockIdx.x;
    int item = bid / 12;
    if (item >= *wcount) return;
    int colt = bid - item * 12;
    int w = wl[item];
    int e = w >> 8, rt = w & 255;
    int beg = offsets[e], ne = offsets[e + 1] - beg;
    int row0 = rt * 128, col0 = colt * 128;

    __shared__ u16 As[2][128 * 32];
    __shared__ u16 Bs[2][128 * 32];

    int tid = threadIdx.x;
    int wave = tid >> 6, lane = tid & 63;
    int wm = wave & 1, wn = wave >> 1;

    int koff = (((lane & 3) ^ ((lane >> 3) & 3)) * 8);
    const u16* aptr[2];
    const u16* bptr[2];
    #pragma unroll
    for (int q = 0; q < 2; q++) {
        int lrow = wave * 32 + q * 16 + (lane >> 2);
        int gi = beg + row0 + lrow;
        int gi2 = (row0 + lrow < ne) ? gi : beg;     // clamp OOB rows to a valid row
        int tok = tlist[gi2] >> 1;
        aptr[q] = xb + (size_t)tok * DIM + koff;
        int n = col0 + lrow;                          // B row = output col, always < HID
        bptr[q] = w1b + (size_t)(e * HID + n) * DIM + koff;
    }

    int rchunk = (((lane >> 4) ^ ((lane >> 1) & 3)) * 8);

    floatx4 acc[4][4] = {};
    // prologue: stage tile 0
    #pragma unroll
    for (int q = 0; q < 2; q++) {
        GLOAD_LDS16(aptr[q], &As[0][(wave * 32 + q * 16) * 32]);
        GLOAD_LDS16(bptr[q], &Bs[0][(wave * 32 + q * 16) * 32]);
    }
    __syncthreads();
    int cur = 0;
    for (int k0 = 0; k0 < DIM; k0 += 32) {
        if (k0 + 32 < DIM) {
            #pragma unroll
            for (int q = 0; q < 2; q++) {
                GLOAD_LDS16(aptr[q] + k0 + 32, &As[cur ^ 1][(wave * 32 + q * 16) * 32]);
                GLOAD_LDS16(bptr[q] + k0 + 32, &Bs[cur ^ 1][(wave * 32 + q * 16) * 32]);
            }
        }
        short8 af[4], bf_[4];
        #pragma unroll
        for (int mi = 0; mi < 4; mi++)
            af[mi] = *(const short8*)&As[cur][(wm * 64 + mi * 16 + (lane & 15)) * 32 + rchunk];
        #pragma unroll
        for (int nj = 0; nj < 4; nj++)
            bf_[nj] = *(const short8*)&Bs[cur][(wn * 64 + nj * 16 + (lane & 15)) * 32 + rchunk];
        #pragma unroll
        for (int mi = 0; mi < 4; mi++)
            #pragma unroll
            for (int nj = 0; nj < 4; nj++)
                acc[mi][nj] = __builtin_amdgcn_mfma_f32_16x16x32_bf16(af[mi], bf_[nj], acc[mi][nj], 0, 0, 0);
        __syncthreads();
        cur ^= 1;
    }

    #pragma unroll
    for (int mi = 0; mi < 4; mi++) {
        #pragma unroll
        for (int r = 0; r < 4; r++) {
            int lrow = wm * 64 + mi * 16 + (lane >> 4) * 4 + r;
            if (row0 + lrow >= ne) continue;
            size_t orow = (size_t)(beg + row0 + lrow);
            #pragma unroll
            for (int nj = 0; nj < 4; nj++) {
                int col = col0 + wn * 64 + nj * 16 + (lane & 15);
                float v = acc[mi][nj][r] + b1[e * HID + col];
                __hip_bfloat16 hb = __float2bfloat16(gelu_tanh(v));
                h_bf[orow * HID + col] = *(u16*)&hb;
            }
        }
    }
}

// GEMM2: out[tok(a)] += gate(a) * (h[a] @ w2[e]^T + b2[e]),  K=HID=1536, N=DIM=1024
// 2-way K-split (out is an fp32 atomic combine already; bias added by split 0).
__global__ __launch_bounds__(256)
void gemm2_kernel(const u16* __restrict__ h_bf, const u16* __restrict__ w2b,
                  const float* __restrict__ b2,
                  const int* __restrict__ offsets, const int* __restrict__ tlist,
                  const int* __restrict__ wl, const int* __restrict__ wcount,
                  const float* __restrict__ gate, float* __restrict__ out) {
    int bid = blockIdx.x;
    int item = bid >> 4;
    if (item >= *wcount) return;
    int colt = bid & 7;
    int ks = (bid >> 3) & 1;
    int w = wl[item];
    int e = w >> 8, rt = w & 255;
    int beg = offsets[e], ne = offsets[e + 1] - beg;
    int row0 = rt * 128, col0 = colt * 128;
    int kbeg = ks * (HID / 2);
    int kend = kbeg + (HID / 2);

    __shared__ u16 As[2][128 * 32];
    __shared__ u16 Bs[2][128 * 32];

    int tid = threadIdx.x;
    int wave = tid >> 6, lane = tid & 63;
    int wm = wave & 1, wn = wave >> 1;

    int koff = (((lane & 3) ^ ((lane >> 3) & 3)) * 8);
    const u16* aptr[2];
    const u16* bptr[2];
    #pragma unroll
    for (int q = 0; q < 2; q++) {
        int lrow = wave * 32 + q * 16 + (lane >> 2);
        int gi = beg + row0 + lrow;
        int gi2 = (row0 + lrow < ne) ? gi : beg;
        aptr[q] = h_bf + (size_t)gi2 * HID + koff;
        int n = col0 + lrow;                          // < DIM always
        bptr[q] = w2b + (size_t)(e * DIM + n) * HID + koff;
    }

    int rchunk = (((lane >> 4) ^ ((lane >> 1) & 3)) * 8);

    floatx4 acc[4][4] = {};
    // prologue: stage first tile of this K-half
    #pragma unroll
    for (int q = 0; q < 2; q++) {
        GLOAD_LDS16(aptr[q] + kbeg, &As[0][(wave * 32 + q * 16) * 32]);
        GLOAD_LDS16(bptr[q] + kbeg, &Bs[0][(wave * 32 + q * 16) * 32]);
    }
    __syncthreads();
    int cur = 0;
    for (int k0 = kbeg; k0 < kend; k0 += 32) {
        if (k0 + 32 < kend) {
            #pragma unroll
            for (int q = 0; q < 2; q++) {
                GLOAD_LDS16(aptr[q] + k0 + 32, &As[cur ^ 1][(wave * 32 + q * 16) * 32]);
                GLOAD_LDS16(bptr[q] + k0 + 32, &Bs[cur ^ 1][(wave * 32 + q * 16) * 32]);
            }
        }
        short8 af[4], bf_[4];
        #pragma unroll
        for (int mi = 0; mi < 4; mi++)
            af[mi] = *(const short8*)&As[cur][(wm * 64 + mi * 16 + (lane & 15)) * 32 + rchunk];
        #pragma unroll
        for (int nj = 0; nj < 4; nj++)
            bf_[nj] = *(const short8*)&Bs[cur][(wn * 64 + nj * 16 + (lane & 15)) * 32 + rchunk];
        #pragma unroll
        for (int mi = 0; mi < 4; mi++)
            #pragma unroll
            for (int nj = 0; nj < 4; nj++)
                acc[mi][nj] = __builtin_amdgcn_mfma_f32_16x16x32_bf16(af[mi], bf_[nj], acc[mi][nj], 0, 0, 0);
        __syncthreads();
        cur ^= 1;
    }

    #pragma unroll
    for (int mi = 0; mi < 4; mi++) {
        #pragma unroll
        for (int r = 0; r < 4; r++) {
            int lrow = wm * 64 + mi * 16 + (lane >> 4) * 4 + r;
            if (row0 + lrow >= ne) continue;
            int t = tlist[beg + row0 + lrow];
            float g = gate[t];
            int tok = t >> 1;
            #pragma unroll
            for (int nj = 0; nj < 4; nj++) {
                int col = col0 + wn * 64 + nj * 16 + (lane & 15);
                float v = acc[mi][nj][r];
                if (ks == 0) v += b2[e * DIM + col];
                v *= g;
                atomicAdd(&out[(size_t)tok * DIM + col], v);
            }
        }
    }
}

extern "C" void kernel_launch(void* const* d_in, const int* in_sizes, int n_in,
                              void* d_out, int out_size, void* d_ws, size_t ws_size,
                              hipStream_t stream) {
    const float* x  = (const float*)d_in[0];
    const float* rw = (const float*)d_in[1];
    const float* w1 = (const float*)d_in[2];
    const float* b1 = (const float*)d_in[3];
    const float* w2 = (const float*)d_in[4];
    const float* b2 = (const float*)d_in[5];
    float* out = (float*)d_out;   // fp32 output [N*D main | 1 aux]

    // ---- workspace layout (bytes) ----
    char* ws = (char*)d_ws;
    int*   offsets = (int*)(ws + 192);        // 17
    int*   wcount  = (int*)(ws + 384);        // 1
    int*   wl      = (int*)(ws + 512);        // up to 128
    int*   idx     = (int*)(ws + 4096);                               // 32 KB
    float* gate    = (float*)(ws + 4096 + 4 * NASSIGN);               // 32 KB
    int*   tlist   = (int*)(ws + 4096 + 8 * NASSIGN);                 // 32 KB
    u16*   x_bf    = (u16*)(ws + (128 << 10));                        // 8 MB
    u16*   h_bf    = x_bf + (size_t)N_TOK * DIM;                      // 25.2 MB
    u16*   w_bf    = h_bf + (size_t)NASSIGN * HID;                    // 50.3 MB (w1 then w2)

    hipMemsetAsync(d_out, 0, (size_t)out_size * 4, stream); // zero for atomic combine

    cvt_kernel<<<(NEXP * HID * DIM / 4 + 255) / 256, 256, 0, stream>>>(w1, w_bf, NEXP * HID * DIM / 4);

    logits_topk_kernel<<<N_TOK / 16, 256, 0, stream>>>(x, rw, idx, gate, x_bf);
    plan_kernel<<<1, 256, 0, stream>>>(idx, gate, offsets, tlist, wl, wcount,
                                       out + (size_t)N_TOK * DIM);

    gemm1_kernel<<<MAX_ITEMS * 12, 256, 0, stream>>>(
        x_bf, w_bf, b1, offsets, tlist, wl, wcount, h_bf);

    cvt_kernel<<<(NEXP * DIM * HID / 4 + 255) / 256, 256, 0, stream>>>(w2, w_bf, NEXP * DIM * HID / 4);

    gemm2_kernel<<<MAX_ITEMS * 16, 256, 0, stream>>>(
        h_bf, w_bf, b2, offsets, tlist, wl, wcount, gate, out);
}

// Round 2
// 402.748 us; speedup vs baseline: 1.2095x; 1.2095x over previous
//
#include <hip/hip_runtime.h>
#include <hip/hip_bf16.h>
#include <math.h>

// Problem constants (fixed by the reference)
#define N_TOK 4096
#define DIM   1024
#define NEXP  16
#define HID   1536
#define TOPK2 2
#define NASSIGN (N_TOK * TOPK2)   // 8192

#define MAX_ITEMS 80      // worst-case sum_e ceil(ne/128) = 79
#define G1_BLOCKS (MAX_ITEMS * 12)          // 960 gemm1 tile blocks
#define W_ELEMS   (NEXP * HID * DIM)        // 25,165,824 (w1 and w2 same size)
#define CVT_BLOCKS (W_ELEMS / 4 / 256)      // 24576 blocks of 256 float4-threads

typedef __attribute__((ext_vector_type(8))) short short8;   // bf16x8 MFMA A/B frag
typedef __attribute__((ext_vector_type(4))) float floatx4;  // fp32x4 MFMA C/D frag
typedef unsigned short u16;

// async global->LDS, 16B per lane; LDS dest = wave-uniform base + lane*16
#define GLOAD_LDS16(gp, lp)                                                     \
    __builtin_amdgcn_global_load_lds(                                           \
        (const __attribute__((address_space(1))) unsigned int*)(gp),            \
        (__attribute__((address_space(3))) unsigned int*)(lp), 16, 0, 0)

__device__ __forceinline__ void cvt_one4(const float* __restrict__ src,
                                         u16* __restrict__ dst, int i) {
    float4 v = ((const float4*)src)[i];
    __hip_bfloat16 a = __float2bfloat16(v.x), b = __float2bfloat16(v.y);
    __hip_bfloat16 c = __float2bfloat16(v.z), d = __float2bfloat16(v.w);
    ushort4 o;
    o.x = *(u16*)&a; o.y = *(u16*)&b; o.z = *(u16*)&c; o.w = *(u16*)&d;
    ((ushort4*)dst)[i] = o;
}

// ---------------- standalone fp32 -> bf16 conversion (fallback path) ----------------
__global__ void cvt_kernel(const float* __restrict__ src, u16* __restrict__ dst, int n4) {
    int i = blockIdx.x * 256 + threadIdx.x;
    if (i >= n4) return;
    cvt_one4(src, dst, i);
}

// ---------- Router logits + top-2 + gates + x->bf16, FUSED with w1 fp32->bf16 ----------
// Blocks [0,256): router (16 tokens each). Blocks [256, 256+CVT_BLOCKS): stream-convert w1.
// Router is latency-bound on ~256 CUs; the BW-bound cvt fills the rest (separate pipes overlap).
__global__ __launch_bounds__(256)
void router_cvtw1_kernel(const float* __restrict__ x, const float* __restrict__ rw,
                         int* __restrict__ idx, float* __restrict__ gate,
                         u16* __restrict__ x_bf,
                         const float* __restrict__ w1src, u16* __restrict__ w1dst) {
    int tid = threadIdx.x;
    if (blockIdx.x >= 256) {
        int i = (blockIdx.x - 256) * 256 + tid;   // exactly W_ELEMS/4 items
        cvt_one4(w1src, w1dst, i);
        return;
    }
    int tb = blockIdx.x * 16;
    __shared__ float xs[16][68];
    __shared__ float rs[16][68];
    __shared__ float lg[16][17];

    int t = tid >> 4, e = tid & 15;
    int srow = tid >> 4, scol = (tid & 15) * 4;   // staging: one float4/thread

    float acc = 0.f;
    for (int k0 = 0; k0 < DIM; k0 += 64) {
        float4 xv = *(const float4*)&x[(size_t)(tb + srow) * DIM + k0 + scol];
        *(float4*)&xs[srow][scol] = xv;
        *(float4*)&rs[srow][scol] = *(const float4*)&rw[(size_t)srow * DIM + k0 + scol];
        {   // fused x -> bf16
            __hip_bfloat16 a = __float2bfloat16(xv.x), b = __float2bfloat16(xv.y);
            __hip_bfloat16 c = __float2bfloat16(xv.z), d = __float2bfloat16(xv.w);
            ushort4 o;
            o.x = *(u16*)&a; o.y = *(u16*)&b; o.z = *(u16*)&c; o.w = *(u16*)&d;
            *(ushort4*)&x_bf[(size_t)(tb + srow) * DIM + k0 + scol] = o;
        }
        __syncthreads();
        const float2* xp = (const float2*)xs[t];
        const float2* rp = (const float2*)rs[e];
        #pragma unroll
        for (int k = 0; k < 32; k++) {
            float2 a = xp[k], b = rp[k];
            acc = fmaf(a.x, b.x, acc);
            acc = fmaf(a.y, b.y, acc);
        }
        __syncthreads();
    }
    lg[t][e] = acc;
    __syncthreads();

    if (tid < 16) {
        int n = tb + tid;
        float v0 = -3.402823466e+38f, v1 = -3.402823466e+38f;
        int i0 = 0, i1 = 0;
        #pragma unroll
        for (int ee = 0; ee < NEXP; ee++) {
            float v = lg[tid][ee];
            if (v > v0) { v1 = v0; i1 = i0; v0 = v; i0 = ee; }
            else if (v > v1) { v1 = v; i1 = ee; }
        }
        float e1 = expf(v1 - v0);
        float inv = 1.f / (1.f + e1);
        idx[2 * n] = i0; idx[2 * n + 1] = i1;
        gate[2 * n] = inv; gate[2 * n + 1] = e1 * inv;
    }
}

// ---- Plan: counts/gsum -> offsets + aux + worklist + scatter + inverse map ----
__global__ __launch_bounds__(256)
void plan_kernel(const int* __restrict__ idx, const float* __restrict__ gate,
                 int* __restrict__ offsets, int* __restrict__ tlist,
                 int* __restrict__ slot_of,
                 int* __restrict__ wl, int* __restrict__ wcount,
                 float* __restrict__ aux_out) {
    __shared__ int cnt_s[16];
    __shared__ float gs_s[16];
    __shared__ int pos_s[16];
    __shared__ int offs_s[17];
    int tid = threadIdx.x;
    if (tid < 16) { cnt_s[tid] = 0; gs_s[tid] = 0.f; pos_s[tid] = 0; }
    __syncthreads();
    for (int i = tid; i < NASSIGN; i += 256) {
        int e = idx[i];
        atomicAdd(&cnt_s[e], 1);
        atomicAdd(&gs_s[e], gate[i]);
    }
    __syncthreads();
    if (tid == 0) {
        int acc = 0;
        for (int e = 0; e < NEXP; e++) { offs_s[e] = acc; acc += cnt_s[e]; }
        offs_s[NEXP] = acc;
        float tot = (float)acc;
        float s = 0.f;
        for (int e = 0; e < NEXP; e++) {
            float c = (float)cnt_s[e];
            s += (c / tot) * (gs_s[e] / fmaxf(c, 1.f));
        }
        *aux_out = 0.02f * (s / (float)NEXP);
        int m = 0;
        for (int e = 0; e < NEXP; e++) {
            int nt = (cnt_s[e] + 127) >> 7;
            for (int rt = 0; rt < nt; rt++) wl[m++] = (e << 8) | rt;
        }
        *wcount = m;
    }
    __syncthreads();
    if (tid < 17) offsets[tid] = offs_s[tid];
    for (int i = tid; i < NASSIGN; i += 256) {
        int e = idx[i];
        int p = atomicAdd(&pos_s[e], 1);
        int s = offs_s[e] + p;
        tlist[s] = i;
        slot_of[i] = s;
    }
}

__device__ __forceinline__ float gelu_tanh(float v) {
    float v3 = v * v * v;
    float t = tanhf(0.7978845608028654f * (v + 0.044715f * v3));
    return 0.5f * v * (1.f + t);
}

// =====================================================================
// MFMA grouped GEMM, 128x128 tile, BK=32 bf16, 4 waves (each 64x64).
// Double-buffered LDS: stage next K-tile before compute, one barrier/step.
// =====================================================================

// GEMM1: h[a, :] = gelu(x[tok(a)] @ w1[e]^T + b1[e]),  K=DIM=1024, N=HID=1536
// FUSED: blocks >= G1_BLOCKS stream-convert w2 fp32->bf16 (hidden under gemm1's
// latency-bound execution; gemm2 in stream order sees it complete).
__global__ __launch_bounds__(256)
void gemm1_cvtw2_kernel(const u16* __restrict__ xb, const u16* __restrict__ w1b,
                        const float* __restrict__ b1,
                        const int* __restrict__ offsets, const int* __restrict__ tlist,
                        const int* __restrict__ wl, const int* __restrict__ wcount,
                        u16* __restrict__ h_bf,
                        const float* __restrict__ w2src, u16* __restrict__ w2dst) {
    int bid = blockIdx.x;
    int tid = threadIdx.x;
    if (bid >= G1_BLOCKS) {
        int i = (bid - G1_BLOCKS) * 256 + tid;    // exactly W_ELEMS/4 items when launched fused
        cvt_one4(w2src, w2dst, i);
        return;
    }
    int item = bid / 12;
    if (item >= *wcount) return;
    int colt = bid - item * 12;
    int w = wl[item];
    int e = w >> 8, rt = w & 255;
    int beg = offsets[e], ne = offsets[e + 1] - beg;
    int row0 = rt * 128, col0 = colt * 128;

    __shared__ u16 As[2][128 * 32];
    __shared__ u16 Bs[2][128 * 32];

    int wave = tid >> 6, lane = tid & 63;
    int wm = wave & 1, wn = wave >> 1;

    int koff = (((lane & 3) ^ ((lane >> 3) & 3)) * 8);
    const u16* aptr[2];
    const u16* bptr[2];
    #pragma unroll
    for (int q = 0; q < 2; q++) {
        int lrow = wave * 32 + q * 16 + (lane >> 2);
        int gi = beg + row0 + lrow;
        int gi2 = (row0 + lrow < ne) ? gi : beg;     // clamp OOB rows to a valid row
        int tok = tlist[gi2] >> 1;
        aptr[q] = xb + (size_t)tok * DIM + koff;
        int n = col0 + lrow;                          // B row = output col, always < HID
        bptr[q] = w1b + (size_t)(e * HID + n) * DIM + koff;
    }

    int rchunk = (((lane >> 4) ^ ((lane >> 1) & 3)) * 8);

    floatx4 acc[4][4] = {};
    #pragma unroll
    for (int q = 0; q < 2; q++) {
        GLOAD_LDS16(aptr[q], &As[0][(wave * 32 + q * 16) * 32]);
        GLOAD_LDS16(bptr[q], &Bs[0][(wave * 32 + q * 16) * 32]);
    }
    __syncthreads();
    int cur = 0;
    for (int k0 = 0; k0 < DIM; k0 += 32) {
        if (k0 + 32 < DIM) {
            #pragma unroll
            for (int q = 0; q < 2; q++) {
                GLOAD_LDS16(aptr[q] + k0 + 32, &As[cur ^ 1][(wave * 32 + q * 16) * 32]);
                GLOAD_LDS16(bptr[q] + k0 + 32, &Bs[cur ^ 1][(wave * 32 + q * 16) * 32]);
            }
        }
        short8 af[4], bf_[4];
        #pragma unroll
        for (int mi = 0; mi < 4; mi++)
            af[mi] = *(const short8*)&As[cur][(wm * 64 + mi * 16 + (lane & 15)) * 32 + rchunk];
        #pragma unroll
        for (int nj = 0; nj < 4; nj++)
            bf_[nj] = *(const short8*)&Bs[cur][(wn * 64 + nj * 16 + (lane & 15)) * 32 + rchunk];
        #pragma unroll
        for (int mi = 0; mi < 4; mi++)
            #pragma unroll
            for (int nj = 0; nj < 4; nj++)
                acc[mi][nj] = __builtin_amdgcn_mfma_f32_16x16x32_bf16(af[mi], bf_[nj], acc[mi][nj], 0, 0, 0);
        __syncthreads();
        cur ^= 1;
    }

    #pragma unroll
    for (int mi = 0; mi < 4; mi++) {
        #pragma unroll
        for (int r = 0; r < 4; r++) {
            int lrow = wm * 64 + mi * 16 + (lane >> 4) * 4 + r;
            if (row0 + lrow >= ne) continue;
            size_t orow = (size_t)(beg + row0 + lrow);
            #pragma unroll
            for (int nj = 0; nj < 4; nj++) {
                int col = col0 + wn * 64 + nj * 16 + (lane & 15);
                float v = acc[mi][nj][r] + b1[e * HID + col];
                __hip_bfloat16 hb = __float2bfloat16(gelu_tanh(v));
                h_bf[orow * HID + col] = *(u16*)&hb;
            }
        }
    }
}

// GEMM2: y[a] = gate(a) * (h[a] @ w2[e]^T + b2[e]),  K=HID=1536, N=DIM=1024
// use_y=1: plain coalesced stores to per-assignment y (combined later — NO atomics).
// use_y=0: fallback, atomicAdd directly into out.
__global__ __launch_bounds__(256)
void gemm2_kernel(const u16* __restrict__ h_bf, const u16* __restrict__ w2b,
                  const float* __restrict__ b2,
                  const int* __restrict__ offsets, const int* __restrict__ tlist,
                  const int* __restrict__ wl, const int* __restrict__ wcount,
                  const float* __restrict__ gate, float* __restrict__ ydst,
                  int use_y) {
    int bid = blockIdx.x;
    int item = bid >> 3;
    if (item >= *wcount) return;
    int colt = bid & 7;
    int w = wl[item];
    int e = w >> 8, rt = w & 255;
    int beg = offsets[e], ne = offsets[e + 1] - beg;
    int row0 = rt * 128, col0 = colt * 128;

    __shared__ u16 As[2][128 * 32];
    __shared__ u16 Bs[2][128 * 32];

    int tid = threadIdx.x;
    int wave = tid >> 6, lane = tid & 63;
    int wm = wave & 1, wn = wave >> 1;

    int koff = (((lane & 3) ^ ((lane >> 3) & 3)) * 8);
    const u16* aptr[2];
    const u16* bptr[2];
    #pragma unroll
    for (int q = 0; q < 2; q++) {
        int lrow = wave * 32 + q * 16 + (lane >> 2);
        int gi = beg + row0 + lrow;
        int gi2 = (row0 + lrow < ne) ? gi : beg;
        aptr[q] = h_bf + (size_t)gi2 * HID + koff;
        int n = col0 + lrow;                          // < DIM always
        bptr[q] = w2b + (size_t)(e * DIM + n) * HID + koff;
    }

    int rchunk = (((lane >> 4) ^ ((lane >> 1) & 3)) * 8);

    floatx4 acc[4][4] = {};
    #pragma unroll
    for (int q = 0; q < 2; q++) {
        GLOAD_LDS16(aptr[q], &As[0][(wave * 32 + q * 16) * 32]);
        GLOAD_LDS16(bptr[q], &Bs[0][(wave * 32 + q * 16) * 32]);
    }
    __syncthreads();
    int cur = 0;
    for (int k0 = 0; k0 < HID; k0 += 32) {
        if (k0 + 32 < HID) {
            #pragma unroll
            for (int q = 0; q < 2; q++) {
                GLOAD_LDS16(aptr[q] + k0 + 32, &As[cur ^ 1][(wave * 32 + q * 16) * 32]);
                GLOAD_LDS16(bptr[q] + k0 + 32, &Bs[cur ^ 1][(wave * 32 + q * 16) * 32]);
            }
        }
        short8 af[4], bf_[4];
        #pragma unroll
        for (int mi = 0; mi < 4; mi++)
            af[mi] = *(const short8*)&As[cur][(wm * 64 + mi * 16 + (lane & 15)) * 32 + rchunk];
        #pragma unroll
        for (int nj = 0; nj < 4; nj++)
            bf_[nj] = *(const short8*)&Bs[cur][(wn * 64 + nj * 16 + (lane & 15)) * 32 + rchunk];
        #pragma unroll
        for (int mi = 0; mi < 4; mi++)
            #pragma unroll
            for (int nj = 0; nj < 4; nj++)
                acc[mi][nj] = __builtin_amdgcn_mfma_f32_16x16x32_bf16(af[mi], bf_[nj], acc[mi][nj], 0, 0, 0);
        __syncthreads();
        cur ^= 1;
    }

    #pragma unroll
    for (int mi = 0; mi < 4; mi++) {
        #pragma unroll
        for (int r = 0; r < 4; r++) {
            int lrow = wm * 64 + mi * 16 + (lane >> 4) * 4 + r;
            if (row0 + lrow >= ne) continue;
            int slot = beg + row0 + lrow;
            int t = tlist[slot];
            float g = gate[t];
            if (use_y) {
                #pragma unroll
                for (int nj = 0; nj < 4; nj++) {
                    int col = col0 + wn * 64 + nj * 16 + (lane & 15);
                    float v = g * (acc[mi][nj][r] + b2[e * DIM + col]);
                    ydst[(size_t)slot * DIM + col] = v;
                }
            } else {
                int tok = t >> 1;
                #pragma unroll
                for (int nj = 0; nj < 4; nj++) {
                    int col = col0 + wn * 64 + nj * 16 + (lane & 15);
                    float v = g * (acc[mi][nj][r] + b2[e * DIM + col]);
                    atomicAdd(&ydst[(size_t)tok * DIM + col], v);
                }
            }
        }
    }
}

// out[t] = y[slot_of[2t]] + y[slot_of[2t+1]]  — pure streaming, fully coalesced
__global__ __launch_bounds__(256)
void combine_kernel(const float* __restrict__ y, const int* __restrict__ slot_of,
                    float* __restrict__ out) {
    int t = blockIdx.x;
    int c4 = threadIdx.x;                      // 256 float4 = 1024 floats
    int s0 = slot_of[2 * t], s1 = slot_of[2 * t + 1];
    float4 a = ((const float4*)(y + (size_t)s0 * DIM))[c4];
    float4 b = ((const float4*)(y + (size_t)s1 * DIM))[c4];
    float4 o;
    o.x = a.x + b.x; o.y = a.y + b.y; o.z = a.z + b.z; o.w = a.w + b.w;
    ((float4*)(out + (size_t)t * DIM))[c4] = o;
}

extern "C" void kernel_launch(void* const* d_in, const int* in_sizes, int n_in,
                              void* d_out, int out_size, void* d_ws, size_t ws_size,
                              hipStream_t stream) {
    const float* x  = (const float*)d_in[0];
    const float* rw = (const float*)d_in[1];
    const float* w1 = (const float*)d_in[2];
    const float* b1 = (const float*)d_in[3];
    const float* w2 = (const float*)d_in[4];
    const float* b2 = (const float*)d_in[5];
    float* out = (float*)d_out;   // fp32 output [N*D main | 1 aux]

    // ---- workspace layout (bytes) ----
    char* ws = (char*)d_ws;
    int*   offsets = (int*)(ws + 192);        // 17
    int*   wcount  = (int*)(ws + 384);        // 1
    int*   wl      = (int*)(ws + 512);        // up to 128
    int*   idx     = (int*)(ws + 4096);                               // 32 KB
    float* gate    = (float*)(ws + 4096 + 4 * NASSIGN);               // 32 KB
    int*   tlist   = (int*)(ws + 4096 + 8 * NASSIGN);                 // 32 KB
    int*   slot_of = (int*)(ws + 4096 + 12 * NASSIGN);                // 32 KB
    u16*   x_bf    = (u16*)(ws + (256 << 10));                        // 8 MB
    u16*   h_bf    = x_bf + (size_t)N_TOK * DIM;                      // +25.2 MB
    u16*   w1_bf   = h_bf + (size_t)NASSIGN * HID;                    // +50.3 MB
    u16*   w2_bf   = w1_bf + (size_t)W_ELEMS;                         // +50.3 MB (full path)

    const size_t NEED_FULL = (size_t)(256 << 10)
                           + (size_t)N_TOK * DIM * 2
                           + (size_t)NASSIGN * HID * 2
                           + (size_t)W_ELEMS * 2 * 2;                 // = 134,479,872
    int full = (ws_size >= NEED_FULL) ? 1 : 0;

    if (full) {
        // y (8192*1024 fp32 = 33.5 MB) aliases the w1_bf region (dead after gemm1)
        float* y = (float*)w1_bf;

        // router + x->bf16, fused with w1 fp32->bf16 (fills idle CUs/BW)
        router_cvtw1_kernel<<<256 + CVT_BLOCKS, 256, 0, stream>>>(
            x, rw, idx, gate, x_bf, w1, w1_bf);
        plan_kernel<<<1, 256, 0, stream>>>(idx, gate, offsets, tlist, slot_of,
                                           wl, wcount, out + (size_t)N_TOK * DIM);
        // gemm1, fused with w2 fp32->bf16 (hidden under gemm1's latency-bound run)
        gemm1_cvtw2_kernel<<<G1_BLOCKS + CVT_BLOCKS, 256, 0, stream>>>(
            x_bf, w1_bf, b1, offsets, tlist, wl, wcount, h_bf, w2, w2_bf);
        // gemm2 -> per-assignment y (plain stores, no atomics)
        gemm2_kernel<<<MAX_ITEMS * 8, 256, 0, stream>>>(
            h_bf, w2_bf, b2, offsets, tlist, wl, wcount, gate, y, 1);
        // combine two assignments per token (out fully written; no memset needed)
        combine_kernel<<<N_TOK, 256, 0, stream>>>(y, slot_of, out);
    } else {
        // Fallback: proven round-0 structure (shared weight buffer, atomic combine)
        u16* w_bf = w1_bf;
        hipMemsetAsync(d_out, 0, (size_t)out_size * 4, stream);
        router_cvtw1_kernel<<<256 + CVT_BLOCKS, 256, 0, stream>>>(
            x, rw, idx, gate, x_bf, w1, w_bf);
        plan_kernel<<<1, 256, 0, stream>>>(idx, gate, offsets, tlist, slot_of,
                                           wl, wcount, out + (size_t)N_TOK * DIM);
        gemm1_cvtw2_kernel<<<G1_BLOCKS, 256, 0, stream>>>(   // no cvt blocks
            x_bf, w_bf, b1, offsets, tlist, wl, wcount, h_bf, w2, w_bf);
        cvt_kernel<<<CVT_BLOCKS, 256, 0, stream>>>(w2, w_bf, W_ELEMS / 4);
        gemm2_kernel<<<MAX_ITEMS * 8, 256, 0, stream>>>(
            h_bf, w_bf, b2, offsets, tlist, wl, wcount, gate, out, 0);
    }
}

// Round 3
// 397.685 us; speedup vs baseline: 1.2249x; 1.0127x over previous
//
#include <hip/hip_runtime.h>
#include <hip/hip_bf16.h>
#include <math.h>

// Problem constants (fixed by the reference)
#define N_TOK 4096
#define DIM   1024
#define NEXP  16
#define HID   1536
#define TOPK2 2
#define NASSIGN (N_TOK * TOPK2)   // 8192

#define MAX_ITEMS 80      // worst-case sum_e ceil(ne/128) = 79
#define G1_BLOCKS (MAX_ITEMS * 12)          // 960 gemm1 tile blocks
#define W_ELEMS   (NEXP * HID * DIM)        // 25,165,824 (w1 and w2 same size)
#define CVT_BLOCKS (W_ELEMS / 4 / 256)      // 24576 blocks of 256 float4-threads

typedef __attribute__((ext_vector_type(8))) short short8;   // bf16x8 MFMA A/B frag
typedef __attribute__((ext_vector_type(4))) float floatx4;  // fp32x4 MFMA C/D frag
typedef unsigned short u16;

// async global->LDS, 16B per lane; LDS dest = wave-uniform base + lane*16
#define GLOAD_LDS16(gp, lp)                                                     \
    __builtin_amdgcn_global_load_lds(                                           \
        (const __attribute__((address_space(1))) unsigned int*)(gp),            \
        (__attribute__((address_space(3))) unsigned int*)(lp), 16, 0, 0)

// counted vmcnt wait (T4): literal N, memory clobber, then sched fence (rule #18)
#define WAITV(N) do {                                              \
    asm volatile("s_waitcnt vmcnt(" #N ")" ::: "memory");          \
    __builtin_amdgcn_sched_barrier(0);                             \
} while (0)
#define BARRIER_RAW() __builtin_amdgcn_s_barrier()

__device__ __forceinline__ void cvt_one4(const float* __restrict__ src,
                                         u16* __restrict__ dst, int i) {
    float4 v = ((const float4*)src)[i];
    __hip_bfloat16 a = __float2bfloat16(v.x), b = __float2bfloat16(v.y);
    __hip_bfloat16 c = __float2bfloat16(v.z), d = __float2bfloat16(v.w);
    ushort4 o;
    o.x = *(u16*)&a; o.y = *(u16*)&b; o.z = *(u16*)&c; o.w = *(u16*)&d;
    ((ushort4*)dst)[i] = o;
}

// ---------------- standalone fp32 -> bf16 conversion (fallback path) ----------------
__global__ void cvt_kernel(const float* __restrict__ src, u16* __restrict__ dst, int n4) {
    int i = blockIdx.x * 256 + threadIdx.x;
    if (i >= n4) return;
    cvt_one4(src, dst, i);
}

// ---------- Router logits + top-2 + gates + x->bf16, FUSED with w1 fp32->bf16 ----------
__global__ __launch_bounds__(256)
void router_cvtw1_kernel(const float* __restrict__ x, const float* __restrict__ rw,
                         int* __restrict__ idx, float* __restrict__ gate,
                         u16* __restrict__ x_bf,
                         const float* __restrict__ w1src, u16* __restrict__ w1dst) {
    int tid = threadIdx.x;
    if (blockIdx.x >= 256) {
        int i = (blockIdx.x - 256) * 256 + tid;   // exactly W_ELEMS/4 items
        cvt_one4(w1src, w1dst, i);
        return;
    }
    int tb = blockIdx.x * 16;
    __shared__ float xs[16][68];
    __shared__ float rs[16][68];
    __shared__ float lg[16][17];

    int t = tid >> 4, e = tid & 15;
    int srow = tid >> 4, scol = (tid & 15) * 4;   // staging: one float4/thread

    float acc = 0.f;
    for (int k0 = 0; k0 < DIM; k0 += 64) {
        float4 xv = *(const float4*)&x[(size_t)(tb + srow) * DIM + k0 + scol];
        *(float4*)&xs[srow][scol] = xv;
        *(float4*)&rs[srow][scol] = *(const float4*)&rw[(size_t)srow * DIM + k0 + scol];
        {   // fused x -> bf16
            __hip_bfloat16 a = __float2bfloat16(xv.x), b = __float2bfloat16(xv.y);
            __hip_bfloat16 c = __float2bfloat16(xv.z), d = __float2bfloat16(xv.w);
            ushort4 o;
            o.x = *(u16*)&a; o.y = *(u16*)&b; o.z = *(u16*)&c; o.w = *(u16*)&d;
            *(ushort4*)&x_bf[(size_t)(tb + srow) * DIM + k0 + scol] = o;
        }
        __syncthreads();
        const float2* xp = (const float2*)xs[t];
        const float2* rp = (const float2*)rs[e];
        #pragma unroll
        for (int k = 0; k < 32; k++) {
            float2 a = xp[k], b = rp[k];
            acc = fmaf(a.x, b.x, acc);
            acc = fmaf(a.y, b.y, acc);
        }
        __syncthreads();
    }
    lg[t][e] = acc;
    __syncthreads();

    if (tid < 16) {
        int n = tb + tid;
        float v0 = -3.402823466e+38f, v1 = -3.402823466e+38f;
        int i0 = 0, i1 = 0;
        #pragma unroll
        for (int ee = 0; ee < NEXP; ee++) {
            float v = lg[tid][ee];
            if (v > v0) { v1 = v0; i1 = i0; v0 = v; i0 = ee; }
            else if (v > v1) { v1 = v; i1 = ee; }
        }
        float e1 = expf(v1 - v0);
        float inv = 1.f / (1.f + e1);
        idx[2 * n] = i0; idx[2 * n + 1] = i1;
        gate[2 * n] = inv; gate[2 * n + 1] = e1 * inv;
    }
}

// ---- Plan: counts/gsum -> offsets + aux + worklist + scatter + inverse map ----
__global__ __launch_bounds__(256)
void plan_kernel(const int* __restrict__ idx, const float* __restrict__ gate,
                 int* __restrict__ offsets, int* __restrict__ tlist,
                 int* __restrict__ slot_of,
                 int* __restrict__ wl, int* __restrict__ wcount,
                 float* __restrict__ aux_out) {
    __shared__ int cnt_s[16];
    __shared__ float gs_s[16];
    __shared__ int pos_s[16];
    __shared__ int offs_s[17];
    int tid = threadIdx.x;
    if (tid < 16) { cnt_s[tid] = 0; gs_s[tid] = 0.f; pos_s[tid] = 0; }
    __syncthreads();
    for (int i = tid; i < NASSIGN; i += 256) {
        int e = idx[i];
        atomicAdd(&cnt_s[e], 1);
        atomicAdd(&gs_s[e], gate[i]);
    }
    __syncthreads();
    if (tid == 0) {
        int acc = 0;
        for (int e = 0; e < NEXP; e++) { offs_s[e] = acc; acc += cnt_s[e]; }
        offs_s[NEXP] = acc;
        float tot = (float)acc;
        float s = 0.f;
        for (int e = 0; e < NEXP; e++) {
            float c = (float)cnt_s[e];
            s += (c / tot) * (gs_s[e] / fmaxf(c, 1.f));
        }
        *aux_out = 0.02f * (s / (float)NEXP);
        int m = 0;
        for (int e = 0; e < NEXP; e++) {
            int nt = (cnt_s[e] + 127) >> 7;
            for (int rt = 0; rt < nt; rt++) wl[m++] = (e << 8) | rt;
        }
        *wcount = m;
    }
    __syncthreads();
    if (tid < 17) offsets[tid] = offs_s[tid];
    for (int i = tid; i < NASSIGN; i += 256) {
        int e = idx[i];
        int p = atomicAdd(&pos_s[e], 1);
        int s = offs_s[e] + p;
        tlist[s] = i;
        slot_of[i] = s;
    }
}

__device__ __forceinline__ float gelu_tanh(float v) {
    float v3 = v * v * v;
    float t = tanhf(0.7978845608028654f * (v + 0.044715f * v3));
    return 0.5f * v * (1.f + t);
}

// =====================================================================
// MFMA grouped GEMM, 128x128 tile, BK=32 bf16, 4 waves (each 64x64).
// Depth-2 pipeline (T3+T4): 3 LDS buffers; each iter stages tile t+2,
// then waits COUNTED vmcnt(8) (tiles t+1,t+2 stay in flight across the
// barrier — never drained to 0 in the main loop). Raw s_barriers; the
// post-MFMA barrier frees buf[t%3] for restage at iter t+1.
// Loads/thread/tile = 4  =>  counted N = 4 * tiles-in-flight.
// =====================================================================

// GEMM1: h[a, :] = gelu(x[tok(a)] @ w1[e]^T + b1[e]),  K=DIM=1024, N=HID=1536
// FUSED: blocks >= G1_BLOCKS stream-convert w2 fp32->bf16.
__global__ __launch_bounds__(256)
void gemm1_cvtw2_kernel(const u16* __restrict__ xb, const u16* __restrict__ w1b,
                        const float* __restrict__ b1,
                        const int* __restrict__ offsets, const int* __restrict__ tlist,
                        const int* __restrict__ wl, const int* __restrict__ wcount,
                        u16* __restrict__ h_bf,
                        const float* __restrict__ w2src, u16* __restrict__ w2dst) {
    int bid = blockIdx.x;
    int tid = threadIdx.x;
    if (bid >= G1_BLOCKS) {
        int i = (bid - G1_BLOCKS) * 256 + tid;    // exactly W_ELEMS/4 items when fused
        cvt_one4(w2src, w2dst, i);
        return;
    }
    int item = bid / 12;
    if (item >= *wcount) return;
    int colt = bid - item * 12;
    int w = wl[item];
    int e = w >> 8, rt = w & 255;
    int beg = offsets[e], ne = offsets[e + 1] - beg;
    int row0 = rt * 128, col0 = colt * 128;

    __shared__ u16 As[3][128 * 32];
    __shared__ u16 Bs[3][128 * 32];

    int wave = tid >> 6, lane = tid & 63;
    int wm = wave & 1, wn = wave >> 1;

    int koff = (((lane & 3) ^ ((lane >> 3) & 3)) * 8);
    const u16* aptr[2];
    const u16* bptr[2];
    #pragma unroll
    for (int q = 0; q < 2; q++) {
        int lrow = wave * 32 + q * 16 + (lane >> 2);
        int gi = beg + row0 + lrow;
        int gi2 = (row0 + lrow < ne) ? gi : beg;     // clamp OOB rows to a valid row
        int tok = tlist[gi2] >> 1;
        aptr[q] = xb + (size_t)tok * DIM + koff;
        int n = col0 + lrow;                          // B row = output col, always < HID
        bptr[q] = w1b + (size_t)(e * HID + n) * DIM + koff;
    }

    int rchunk = (((lane >> 4) ^ ((lane >> 1) & 3)) * 8);

    floatx4 acc[4][4] = {};

    auto STAGE = [&](int kt, int b) {
        #pragma unroll
        for (int q = 0; q < 2; q++) {
            GLOAD_LDS16(aptr[q] + kt * 32, &As[b][(wave * 32 + q * 16) * 32]);
            GLOAD_LDS16(bptr[q] + kt * 32, &Bs[b][(wave * 32 + q * 16) * 32]);
        }
    };
    auto CONSUME = [&](int b) {
        short8 af[4], bf_[4];
        #pragma unroll
        for (int mi = 0; mi < 4; mi++)
            af[mi] = *(const short8*)&As[b][(wm * 64 + mi * 16 + (lane & 15)) * 32 + rchunk];
        #pragma unroll
        for (int nj = 0; nj < 4; nj++)
            bf_[nj] = *(const short8*)&Bs[b][(wn * 64 + nj * 16 + (lane & 15)) * 32 + rchunk];
        #pragma unroll
        for (int mi = 0; mi < 4; mi++)
            #pragma unroll
            for (int nj = 0; nj < 4; nj++)
                acc[mi][nj] = __builtin_amdgcn_mfma_f32_16x16x32_bf16(af[mi], bf_[nj], acc[mi][nj], 0, 0, 0);
    };

    const int NT = DIM / 32;   // 32
    STAGE(0, 0); STAGE(1, 1);
    int bc = 0, bn = 1, bs = 2;
    for (int t = 0; t < NT; ++t) {
        if (t + 2 < NT)      { STAGE(t + 2, bs); WAITV(8); }
        else if (t + 1 < NT) { WAITV(4); }
        else                 { WAITV(0); }
        BARRIER_RAW();                       // tile t resident in LDS for all waves
        CONSUME(bc);
        __builtin_amdgcn_sched_barrier(0);
        BARRIER_RAW();                       // all waves done reading buf bc -> restageable
        int tmp = bc; bc = bn; bn = bs; bs = tmp;
    }

    #pragma unroll
    for (int mi = 0; mi < 4; mi++) {
        #pragma unroll
        for (int r = 0; r < 4; r++) {
            int lrow = wm * 64 + mi * 16 + (lane >> 4) * 4 + r;
            if (row0 + lrow >= ne) continue;
            size_t orow = (size_t)(beg + row0 + lrow);
            #pragma unroll
            for (int nj = 0; nj < 4; nj++) {
                int col = col0 + wn * 64 + nj * 16 + (lane & 15);
                float v = acc[mi][nj][r] + b1[e * HID + col];
                __hip_bfloat16 hb = __float2bfloat16(gelu_tanh(v));
                h_bf[orow * HID + col] = *(u16*)&hb;
            }
        }
    }
}

// GEMM2: y[a] = gate(a) * (h[a] @ w2[e]^T + b2[e]),  K=HID=1536, N=DIM=1024
// use_y=1: plain coalesced stores to per-assignment y (combined later — NO atomics).
// use_y=0: fallback, atomicAdd directly into out.
__global__ __launch_bounds__(256)
void gemm2_kernel(const u16* __restrict__ h_bf, const u16* __restrict__ w2b,
                  const float* __restrict__ b2,
                  const int* __restrict__ offsets, const int* __restrict__ tlist,
                  const int* __restrict__ wl, const int* __restrict__ wcount,
                  const float* __restrict__ gate, float* __restrict__ ydst,
                  int use_y) {
    int bid = blockIdx.x;
    int item = bid >> 3;
    if (item >= *wcount) return;
    int colt = bid & 7;
    int w = wl[item];
    int e = w >> 8, rt = w & 255;
    int beg = offsets[e], ne = offsets[e + 1] - beg;
    int row0 = rt * 128, col0 = colt * 128;

    __shared__ u16 As[3][128 * 32];
    __shared__ u16 Bs[3][128 * 32];

    int tid = threadIdx.x;
    int wave = tid >> 6, lane = tid & 63;
    int wm = wave & 1, wn = wave >> 1;

    int koff = (((lane & 3) ^ ((lane >> 3) & 3)) * 8);
    const u16* aptr[2];
    const u16* bptr[2];
    #pragma unroll
    for (int q = 0; q < 2; q++) {
        int lrow = wave * 32 + q * 16 + (lane >> 2);
        int gi = beg + row0 + lrow;
        int gi2 = (row0 + lrow < ne) ? gi : beg;
        aptr[q] = h_bf + (size_t)gi2 * HID + koff;
        int n = col0 + lrow;                          // < DIM always
        bptr[q] = w2b + (size_t)(e * DIM + n) * HID + koff;
    }

    int rchunk = (((lane >> 4) ^ ((lane >> 1) & 3)) * 8);

    floatx4 acc[4][4] = {};

    auto STAGE = [&](int kt, int b) {
        #pragma unroll
        for (int q = 0; q < 2; q++) {
            GLOAD_LDS16(aptr[q] + kt * 32, &As[b][(wave * 32 + q * 16) * 32]);
            GLOAD_LDS16(bptr[q] + kt * 32, &Bs[b][(wave * 32 + q * 16) * 32]);
        }
    };
    auto CONSUME = [&](int b) {
        short8 af[4], bf_[4];
        #pragma unroll
        for (int mi = 0; mi < 4; mi++)
            af[mi] = *(const short8*)&As[b][(wm * 64 + mi * 16 + (lane & 15)) * 32 + rchunk];
        #pragma unroll
        for (int nj = 0; nj < 4; nj++)
            bf_[nj] = *(const short8*)&Bs[b][(wn * 64 + nj * 16 + (lane & 15)) * 32 + rchunk];
        #pragma unroll
        for (int mi = 0; mi < 4; mi++)
            #pragma unroll
            for (int nj = 0; nj < 4; nj++)
                acc[mi][nj] = __builtin_amdgcn_mfma_f32_16x16x32_bf16(af[mi], bf_[nj], acc[mi][nj], 0, 0, 0);
    };

    const int NT = HID / 32;   // 48
    STAGE(0, 0); STAGE(1, 1);
    int bc = 0, bn = 1, bs = 2;
    for (int t = 0; t < NT; ++t) {
        if (t + 2 < NT)      { STAGE(t + 2, bs); WAITV(8); }
        else if (t + 1 < NT) { WAITV(4); }
        else                 { WAITV(0); }
        BARRIER_RAW();
        CONSUME(bc);
        __builtin_amdgcn_sched_barrier(0);
        BARRIER_RAW();
        int tmp = bc; bc = bn; bn = bs; bs = tmp;
    }

    #pragma unroll
    for (int mi = 0; mi < 4; mi++) {
        #pragma unroll
        for (int r = 0; r < 4; r++) {
            int lrow = wm * 64 + mi * 16 + (lane >> 4) * 4 + r;
            if (row0 + lrow >= ne) continue;
            int slot = beg + row0 + lrow;
            int t = tlist[slot];
            float g = gate[t];
            if (use_y) {
                #pragma unroll
                for (int nj = 0; nj < 4; nj++) {
                    int col = col0 + wn * 64 + nj * 16 + (lane & 15);
                    float v = g * (acc[mi][nj][r] + b2[e * DIM + col]);
                    ydst[(size_t)slot * DIM + col] = v;
                }
            } else {
                int tok = t >> 1;
                #pragma unroll
                for (int nj = 0; nj < 4; nj++) {
                    int col = col0 + wn * 64 + nj * 16 + (lane & 15);
                    float v = g * (acc[mi][nj][r] + b2[e * DIM + col]);
                    atomicAdd(&ydst[(size_t)tok * DIM + col], v);
                }
            }
        }
    }
}

// out[t] = y[slot_of[2t]] + y[slot_of[2t+1]]  — pure streaming, fully coalesced
__global__ __launch_bounds__(256)
void combine_kernel(const float* __restrict__ y, const int* __restrict__ slot_of,
                    float* __restrict__ out) {
    int t = blockIdx.x;
    int c4 = threadIdx.x;                      // 256 float4 = 1024 floats
    int s0 = slot_of[2 * t], s1 = slot_of[2 * t + 1];
    float4 a = ((const float4*)(y + (size_t)s0 * DIM))[c4];
    float4 b = ((const float4*)(y + (size_t)s1 * DIM))[c4];
    float4 o;
    o.x = a.x + b.x; o.y = a.y + b.y; o.z = a.z + b.z; o.w = a.w + b.w;
    ((float4*)(out + (size_t)t * DIM))[c4] = o;
}

extern "C" void kernel_launch(void* const* d_in, const int* in_sizes, int n_in,
                              void* d_out, int out_size, void* d_ws, size_t ws_size,
                              hipStream_t stream) {
    const float* x  = (const float*)d_in[0];
    const float* rw = (const float*)d_in[1];
    const float* w1 = (const float*)d_in[2];
    const float* b1 = (const float*)d_in[3];
    const float* w2 = (const float*)d_in[4];
    const float* b2 = (const float*)d_in[5];
    float* out = (float*)d_out;   // fp32 output [N*D main | 1 aux]

    // ---- workspace layout (bytes) ----
    char* ws = (char*)d_ws;
    int*   offsets = (int*)(ws + 192);        // 17
    int*   wcount  = (int*)(ws + 384);        // 1
    int*   wl      = (int*)(ws + 512);        // up to 128
    int*   idx     = (int*)(ws + 4096);                               // 32 KB
    float* gate    = (float*)(ws + 4096 + 4 * NASSIGN);               // 32 KB
    int*   tlist   = (int*)(ws + 4096 + 8 * NASSIGN);                 // 32 KB
    int*   slot_of = (int*)(ws + 4096 + 12 * NASSIGN);                // 32 KB
    u16*   x_bf    = (u16*)(ws + (256 << 10));                        // 8 MB
    u16*   h_bf    = x_bf + (size_t)N_TOK * DIM;                      // +25.2 MB
    u16*   w1_bf   = h_bf + (size_t)NASSIGN * HID;                    // +50.3 MB
    u16*   w2_bf   = w1_bf + (size_t)W_ELEMS;                         // +50.3 MB (full path)

    const size_t NEED_FULL = (size_t)(256 << 10)
                           + (size_t)N_TOK * DIM * 2
                           + (size_t)NASSIGN * HID * 2
                           + (size_t)W_ELEMS * 2 * 2;                 // = 134,479,872
    int full = (ws_size >= NEED_FULL) ? 1 : 0;

    if (full) {
        // y (8192*1024 fp32 = 33.5 MB) aliases the w1_bf region (dead after gemm1)
        float* y = (float*)w1_bf;

        // router + x->bf16, fused with w1 fp32->bf16 (fills idle CUs/BW)
        router_cvtw1_kernel<<<256 + CVT_BLOCKS, 256, 0, stream>>>(
            x, rw, idx, gate, x_bf, w1, w1_bf);
        plan_kernel<<<1, 256, 0, stream>>>(idx, gate, offsets, tlist, slot_of,
                                           wl, wcount, out + (size_t)N_TOK * DIM);
        // gemm1, fused with w2 fp32->bf16 (hidden under gemm1's latency-bound run)
        gemm1_cvtw2_kernel<<<G1_BLOCKS + CVT_BLOCKS, 256, 0, stream>>>(
            x_bf, w1_bf, b1, offsets, tlist, wl, wcount, h_bf, w2, w2_bf);
        // gemm2 -> per-assignment y (plain stores, no atomics)
        gemm2_kernel<<<MAX_ITEMS * 8, 256, 0, stream>>>(
            h_bf, w2_bf, b2, offsets, tlist, wl, wcount, gate, y, 1);
        // combine two assignments per token (out fully written; no memset needed)
        combine_kernel<<<N_TOK, 256, 0, stream>>>(y, slot_of, out);
    } else {
        // Fallback: proven structure (shared weight buffer, atomic combine)
        u16* w_bf = w1_bf;
        hipMemsetAsync(d_out, 0, (size_t)out_size * 4, stream);
        router_cvtw1_kernel<<<256 + CVT_BLOCKS, 256, 0, stream>>>(
            x, rw, idx, gate, x_bf, w1, w_bf);
        plan_kernel<<<1, 256, 0, stream>>>(idx, gate, offsets, tlist, slot_of,
                                           wl, wcount, out + (size_t)N_TOK * DIM);
        gemm1_cvtw2_kernel<<<G1_BLOCKS, 256, 0, stream>>>(   // no cvt blocks
            x_bf, w_bf, b1, offsets, tlist, wl, wcount, h_bf, w2, w_bf);
        cvt_kernel<<<CVT_BLOCKS, 256, 0, stream>>>(w2, w_bf, W_ELEMS / 4);
        gemm2_kernel<<<MAX_ITEMS * 8, 256, 0, stream>>>(
            h_bf, w_bf, b2, offsets, tlist, wl, wcount, gate, out, 0);
    }
}